// Round 10
// baseline (163.562 us; speedup 1.0000x reference)
//
#include <hip/hip_runtime.h>
#include <hip/hip_bf16.h>

// LightGCN: two rounds of edge aggregation.
//   h[i]   = sum_{e: dst[e]==i} x[src[e]]
//   out[i] = sum_{e: dst[e]==i} relu(h)[src[e]]
//
// Round 22 (split convert from partition; register-staged edges):
//   partition_convert sat at ~45us across R16-R21 regardless of structure.
//   Two self-inflicted binds inside that one dispatch: (a) 3125 convert
//   blocks carried the partition's 43KB static LDS -> 3 blocks/CU for a
//   zero-LDS streaming phase; (b) partition tile blocks re-read dst/src
//   from global in pass B (second dependent-load pass, latency-bound at
//   ~1.2 blocks/CU). Fix: convert becomes its own no-LDS kernel (full
//   occupancy, ~7us), and the partition kernel register-stages each
//   thread's 16 (dst,src) pairs (unrolled, 32 VGPRs) -- loaded ONCE, used
//   for both histogram and placement.
//   - partition: LDS-sorted tile -> run-coalesced span writes (R17).
//   - bin_sort: (nid, src-block) counting sort -> CSR (R20).
//   - aggregate: batch-8 unrolled gathers, 8 loads in flight (R21).
//   - ReLU folded into pass-0 aggregate's bf16 write.

#define N_FEAT    64
#define BIN_SHIFT 7
#define BIN_NODES 128
#define CAPBIN    2048             // edges per bin (mean 1600, +11 sigma)
#define NB_H      784              // >= n_bins (782)
#define NSCAN     1024             // padded hist size for the 4-per-thread scan
#define GSTRIDE   16               // one gcur cursor per 64B line
#define TILE      4096
#define EPT       16               // edges per thread (TILE/256)
#define NPTR      (BIN_NODES + 1)  // nodeptr entries per bin
#define SRCSH     14               // src subkey shift: 8 blocks of 16K nodes

typedef unsigned int u32;
typedef unsigned short u16;
typedef __attribute__((ext_vector_type(8))) unsigned short u16x8;
typedef __attribute__((ext_vector_type(4))) unsigned int u32x4;
typedef __attribute__((ext_vector_type(2))) float f32x2;

__device__ inline u16 f2bf(float f) {          // RTNE
    u32 u = __builtin_bit_cast(u32, f);
    return (u16)((u + 0x7FFFu + ((u >> 16) & 1u)) >> 16);
}

// ---- pass 0: x -> bf16 convert (no LDS, full occupancy) ----
__global__ __launch_bounds__(256) void convert_kernel(
    const float* __restrict__ xf, u16* __restrict__ xb, int n_elems)
{
    int i = ((int)blockIdx.x * 256 + (int)threadIdx.x) * 8;
    if (i < n_elems) {
        float4 a = *(const float4*)(xf + i);
        float4 b = *(const float4*)(xf + i + 4);
        u16x8 r;
        r[0]=f2bf(a.x); r[1]=f2bf(a.y); r[2]=f2bf(a.z); r[3]=f2bf(a.w);
        r[4]=f2bf(b.x); r[5]=f2bf(b.y); r[6]=f2bf(b.z); r[7]=f2bf(b.w);
        *(u16x8*)(xb + i) = r;
    }
}

// ---- pass 1: LDS-sorted tile partition (register-staged edges) ----
__global__ __launch_bounds__(256) void partition_kernel(
    const int* __restrict__ src, const int* __restrict__ dst,
    u32* __restrict__ gcur,        // [n_bins*GSTRIDE] padded cursors (zeroed)
    u32* __restrict__ cbdata,      // [n_bins*CAPBIN] packed (nid7<<17)|src
    int n_edges, int n_bins)
{
    __shared__ u32 hist[NSCAN];        // 4 KB
    __shared__ u32 starts[NSCAN];      // 4 KB (tile-local exclusive prefix)
    __shared__ u32 lpos[NSCAN];        // 4 KB
    __shared__ u32 wcur[NB_H];         // 3.1 KB (global span base per bin)
    __shared__ u32 sortbuf[TILE];      // 16 KB
    __shared__ u16 binid[TILE];        // 8 KB
    __shared__ u32 wsum[4];

    const int tid   = threadIdx.x;
    const int tbase = (int)blockIdx.x * TILE;
    const int tend  = min(tbase + TILE, n_edges);

    for (int i = tid; i < NSCAN; i += 256) { hist[i] = 0; lpos[i] = 0; }
    __syncthreads();

    // Load each thread's EPT edges ONCE into registers; histogram as we go.
    u32 breg[EPT];                     // bin id (or ~0 for OOB)
    u32 preg[EPT];                     // packed (nid7<<17)|src
    #pragma unroll
    for (int k = 0; k < EPT; ++k) {
        int e = tbase + tid + k * 256;
        breg[k] = ~0u;
        if (e < tend) {
            int d = dst[e];
            int s = src[e];
            breg[k] = (u32)d >> BIN_SHIFT;
            preg[k] = ((u32)(d & (BIN_NODES - 1)) << 17) | (u32)s;
            atomicAdd(&hist[breg[k]], 1u);
        }
    }
    __syncthreads();

    // Tile-local exclusive scan of hist[0..NSCAN): 4 slots/thread + wave scan.
    {
        const int b0 = tid * 4;
        u32 h0 = hist[b0], h1 = hist[b0+1], h2 = hist[b0+2], h3 = hist[b0+3];
        u32 s  = h0 + h1 + h2 + h3;
        u32 inc = s;
        #pragma unroll
        for (int d = 1; d < 64; d <<= 1) {
            u32 o = __shfl_up(inc, d);
            if ((tid & 63) >= d) inc += o;
        }
        if ((tid & 63) == 63) wsum[tid >> 6] = inc;
        __syncthreads();
        u32 woff = 0;
        #pragma unroll
        for (int k = 0; k < 4; ++k) if (k < (tid >> 6)) woff += wsum[k];
        u32 excl = woff + inc - s;
        starts[b0]   = excl;
        starts[b0+1] = excl + h0;
        starts[b0+2] = excl + h0 + h1;
        starts[b0+3] = excl + h0 + h1 + h2;
    }
    __syncthreads();

    // Reserve global spans (rotated start to spread cursor-line contention).
    const int rot = (int)(((u32)blockIdx.x * 193u) % (u32)n_bins);
    for (int i = tid; i < n_bins; i += 256) {
        int b = i + rot; if (b >= n_bins) b -= n_bins;
        u32 h = hist[b];
        if (h) wcur[b] = atomicAdd(&gcur[b * GSTRIDE], h);
    }
    __syncthreads();

    // Place from registers (no global re-read).
    #pragma unroll
    for (int k = 0; k < EPT; ++k) {
        if (breg[k] != ~0u) {
            u32 b   = breg[k];
            u32 pos = starts[b] + atomicAdd(&lpos[b], 1u);
            sortbuf[pos] = preg[k];
            binid[pos]   = (u16)b;
        }
    }
    __syncthreads();

    // pass C: linear sweep -> run-coalesced global writes.
    const int cnt = tend - tbase;
    for (int j = tid; j < cnt; j += 256) {
        u32 b   = binid[j];
        u32 rel = wcur[b] + ((u32)j - starts[b]);
        if (rel < CAPBIN)
            cbdata[(size_t)b * CAPBIN + rel] = sortbuf[j];
    }
}

// ---- pass 2: per-bin LDS counting sort by (node, src-block) -> CSR ----
__global__ __launch_bounds__(256) void bin_sort_kernel(
    u32* __restrict__ cbdata,          // in: (nid7<<17)|src   out: src (sorted)
    const u32* __restrict__ gcur,
    u32* __restrict__ nodeptr,         // [n_bins*NPTR] absolute offsets
    int n_bins)
{
    __shared__ u32 hist[NSCAN];        // (nid<<3)|srcblk counters, 4 KB
    __shared__ u32 starts[NSCAN];      // 4 KB
    __shared__ u32 lpos[NSCAN];        // 4 KB
    __shared__ u32 sl[CAPBIN];         // 8 KB staging
    __shared__ u32 wsum[4];

    const int tid = threadIdx.x;
    const int bin = blockIdx.x;
    if (bin >= n_bins) return;

    for (int i = tid; i < NSCAN; i += 256) { hist[i] = 0; lpos[i] = 0; }
    __syncthreads();

    int cnt = (int)gcur[bin * GSTRIDE];
    if (cnt > CAPBIN) cnt = CAPBIN;
    u32* bd = cbdata + (size_t)bin * CAPBIN;

    for (int j = tid; j < cnt; j += 256) {             // count
        u32 p = bd[j];
        u32 key = ((p >> 17) << 3) | ((p & 0x1FFFFu) >> SRCSH);
        atomicAdd(&hist[key], 1u);
    }
    __syncthreads();

    // Exclusive scan of hist[0..1024): 4 slots/thread + wave scan.
    {
        const int b0 = tid * 4;
        u32 h0 = hist[b0], h1 = hist[b0+1], h2 = hist[b0+2], h3 = hist[b0+3];
        u32 s  = h0 + h1 + h2 + h3;
        u32 inc = s;
        #pragma unroll
        for (int d = 1; d < 64; d <<= 1) {
            u32 o = __shfl_up(inc, d);
            if ((tid & 63) >= d) inc += o;
        }
        if ((tid & 63) == 63) wsum[tid >> 6] = inc;
        __syncthreads();
        u32 woff = 0;
        #pragma unroll
        for (int k = 0; k < 4; ++k) if (k < (tid >> 6)) woff += wsum[k];
        u32 excl = woff + inc - s;
        starts[b0]   = excl;
        starts[b0+1] = excl + h0;
        starts[b0+2] = excl + h0 + h1;
        starts[b0+3] = excl + h0 + h1 + h2;
    }
    __syncthreads();

    for (int j = tid; j < cnt; j += 256) {             // place into LDS
        u32 p   = bd[j];
        u32 key = ((p >> 17) << 3) | ((p & 0x1FFFFu) >> SRCSH);
        u32 pos = starts[key] + atomicAdd(&lpos[key], 1u);
        sl[pos] = p & 0x1FFFFu;
    }
    __syncthreads();

    const u32 base = (u32)bin * CAPBIN;
    for (int j = tid; j < cnt; j += 256)               // coalesced writeback
        bd[j] = sl[j];
    if (tid < BIN_NODES)
        nodeptr[(size_t)bin * NPTR + tid] = base + starts[tid << 3];
    if (tid == 0)
        nodeptr[(size_t)bin * NPTR + BIN_NODES] = base + (u32)cnt;
}

// ---- aggregate: one 8-lane group per node, CSR spans, no LDS ----
// pass 0: out_bf[node] = bf16(relu(sum))   pass 1: out_f[node] = sum (fp32)
__global__ __launch_bounds__(256) void aggregate_kernel(
    const u16* __restrict__ xin,
    const u32* __restrict__ csorted,   // sorted src ids
    const u32* __restrict__ nodeptr,
    u16* __restrict__ out_bf,
    float* __restrict__ out_f,
    int n_nodes, int pass)
{
    const int tid  = threadIdx.x;

    const int w    = tid >> 6;
    const int lane = tid & 63;
    const int grp  = lane >> 3;
    const int sub  = lane & 7;           // 16B chunk of the 128B bf16 row
    const char* xc = (const char*)xin;

    const int nl   = w * 8 + grp;        // 0..31
    const int node = (int)blockIdx.x * 32 + nl;
    const int bin  = node >> BIN_SHIFT;
    const int nid  = node & (BIN_NODES - 1);

    const int s0  = (int)nodeptr[(size_t)bin * NPTR + nid];
    const int s1  = (int)nodeptr[(size_t)bin * NPTR + nid + 1];

    f32x2 a0={0.f,0.f}, a1={0.f,0.f}, a2={0.f,0.f}, a3={0.f,0.f};

    // Full batches of 8: compile-time unroll -> 8 independent row loads in
    // flight per wave (vmcnt 7..0).
    int jb = s0;
    for (; jb + 8 <= s1; jb += 8) {
        u32 myid = csorted[jb + sub];
        #pragma unroll
        for (int k = 0; k < 8; ++k) {
            u32 s = (u32)__shfl((int)myid, (lane & 56) + k, 64);
            u32x4 v = *(const u32x4*)(xc + ((size_t)s << 7) + (sub << 4));
            a0 += (f32x2){ __builtin_bit_cast(float, v[0] << 16),
                           __builtin_bit_cast(float, v[0] & 0xFFFF0000u) };
            a1 += (f32x2){ __builtin_bit_cast(float, v[1] << 16),
                           __builtin_bit_cast(float, v[1] & 0xFFFF0000u) };
            a2 += (f32x2){ __builtin_bit_cast(float, v[2] << 16),
                           __builtin_bit_cast(float, v[2] & 0xFFFF0000u) };
            a3 += (f32x2){ __builtin_bit_cast(float, v[3] << 16),
                           __builtin_bit_cast(float, v[3] & 0xFFFF0000u) };
        }
    }
    if (jb < s1) {                       // masked tail (< 8 edges)
        u32 myid = 0;
        if (jb + sub < s1) myid = csorted[jb + sub];
        const int m = s1 - jb;
        #pragma unroll 1
        for (int k = 0; k < m; ++k) {
            u32 s = (u32)__shfl((int)myid, (lane & 56) + k, 64);
            u32x4 v = *(const u32x4*)(xc + ((size_t)s << 7) + (sub << 4));
            a0 += (f32x2){ __builtin_bit_cast(float, v[0] << 16),
                           __builtin_bit_cast(float, v[0] & 0xFFFF0000u) };
            a1 += (f32x2){ __builtin_bit_cast(float, v[1] << 16),
                           __builtin_bit_cast(float, v[1] & 0xFFFF0000u) };
            a2 += (f32x2){ __builtin_bit_cast(float, v[2] << 16),
                           __builtin_bit_cast(float, v[2] & 0xFFFF0000u) };
            a3 += (f32x2){ __builtin_bit_cast(float, v[3] << 16),
                           __builtin_bit_cast(float, v[3] & 0xFFFF0000u) };
        }
    }

    if (node < n_nodes) {
        if (pass == 0) {                 // 64 lanes x 16B: 8 bf16 rows, relu'd
            u16x8 o;
            o[0]=f2bf(fmaxf(a0.x,0.f)); o[1]=f2bf(fmaxf(a0.y,0.f));
            o[2]=f2bf(fmaxf(a1.x,0.f)); o[3]=f2bf(fmaxf(a1.y,0.f));
            o[4]=f2bf(fmaxf(a2.x,0.f)); o[5]=f2bf(fmaxf(a2.y,0.f));
            o[6]=f2bf(fmaxf(a3.x,0.f)); o[7]=f2bf(fmaxf(a3.y,0.f));
            *(u16x8*)(out_bf + (size_t)node * N_FEAT + sub * 8) = o;
        } else {                         // 64 lanes x 32B: 8 fp32 rows
            float* dp = out_f + (size_t)node * N_FEAT + sub * 8;
            *(float4*)dp       = (float4){a0.x, a0.y, a1.x, a1.y};
            *(float4*)(dp + 4) = (float4){a2.x, a2.y, a3.x, a3.y};
        }
    }
}

extern "C" void kernel_launch(void* const* d_in, const int* in_sizes, int n_in,
                              void* d_out, int out_size, void* d_ws, size_t ws_size,
                              hipStream_t stream) {
    const float* x          = (const float*)d_in[0];
    const int*   edge_index = (const int*)d_in[1];

    const int n_edges = in_sizes[1] / 2;          // (2, N_EDGES) row-major
    const int* src = edge_index;                  // row 0
    const int* dst = edge_index + n_edges;        // row 1

    const int n_nodes = out_size / N_FEAT;                      // 100000
    const int n_bins  = (n_nodes + BIN_NODES - 1) >> BIN_SHIFT; // 782
    float* out = (float*)d_out;

    const size_t xb_bytes    = (size_t)out_size * sizeof(u16);             // 12.8 MB
    const size_t hb_bytes    = (size_t)out_size * sizeof(u16);             // 12.8 MB
    const size_t cb_bytes    = (size_t)n_bins * CAPBIN * sizeof(u32);      // 6.4 MB
    const size_t np_bytes    = (size_t)n_bins * NPTR * sizeof(u32);        // 0.4 MB
    const size_t gcur_bytes  = (size_t)NB_H * GSTRIDE * sizeof(u32);       // 50 KB

    char* w = (char*)d_ws;
    u16* xb      = (u16*)w;              w += xb_bytes;
    u16* hb      = (u16*)w;              w += hb_bytes;
    u32* cbdata  = (u32*)w;              w += cb_bytes;
    u32* nodeptr = (u32*)w;              w += np_bytes;
    u32* gcur    = (u32*)w;

    hipMemsetAsync(gcur, 0, gcur_bytes, stream);

    const int conv_blocks = (out_size / 8 + 255) / 256;      // 3125
    convert_kernel<<<conv_blocks, 256, 0, stream>>>(x, xb, out_size);

    const int part_blocks = (n_edges + TILE - 1) / TILE;     // 306
    partition_kernel<<<part_blocks, 256, 0, stream>>>(
        src, dst, gcur, cbdata, n_edges, n_bins);

    bin_sort_kernel<<<n_bins, 256, 0, stream>>>(cbdata, gcur, nodeptr, n_bins);

    const int agg_blocks = (n_nodes + 31) / 32;              // 3125
    aggregate_kernel<<<agg_blocks, 256, 0, stream>>>(xb, cbdata, nodeptr, hb, nullptr, n_nodes, 0);
    aggregate_kernel<<<agg_blocks, 256, 0, stream>>>(hb, cbdata, nodeptr, nullptr, out, n_nodes, 1);
}

// Round 11
// 162.078 us; speedup vs baseline: 1.0092x; 1.0092x over previous
//
#include <hip/hip_runtime.h>
#include <hip/hip_bf16.h>

// LightGCN: two rounds of edge aggregation.
//   h[i]   = sum_{e: dst[e]==i} x[src[e]]
//   out[i] = sum_{e: dst[e]==i} relu(h)[src[e]]
//
// Round 23 (512-thread partition; bin_sort fused into agg0):
//   Budget audit: the 256MiB harness re-poison fill (43us) is inside the
//   timed window (120us ours + 43 fill = 163 measured; retrofits R17 too).
//   Controllable items: partition ~30, agg0 ~30, agg1 ~30.
//   (a) partition: 306 blocks x 4 waves = 1.2 blocks/CU with EPT=16 serial
//       LDS-atomic chains -> 512 threads/block (EPT=8, 8 waves): halves
//       serial chains, doubles latency-hiding waves, same tile size so the
//       run-coalesced writes (R17's win) are untouched.
//   (b) bin_sort read 5MB + wrote 5MB that agg0 immediately re-read. Fuse:
//       agg0 = one block per bin: LDS counting-sort by (nid,src-block),
//       gather ids from LDS (same-address broadcast, no shfl), write sorted
//       list + nodeptr for agg1. One fewer dispatch, ~10MB less traffic.
//   - aggregate pass 1: R21 batch-8 unrolled gathers (8 loads in flight).
//   - ReLU folded into agg0's bf16 write.

#define N_FEAT    64
#define BIN_SHIFT 7
#define BIN_NODES 128
#define CAPBIN    2048             // edges per bin (mean 1600, +11 sigma)
#define NB_H      784              // >= n_bins (782)
#define NSCAN     1024             // padded hist size for scans
#define GSTRIDE   16               // one gcur cursor per 64B line
#define TILE      4096
#define PTHREADS  512
#define EPT       8                // edges per thread (TILE/PTHREADS)
#define NPTR      (BIN_NODES + 1)  // nodeptr entries per bin
#define SRCSH     14               // src subkey shift: 8 blocks of 16K nodes

typedef unsigned int u32;
typedef unsigned short u16;
typedef __attribute__((ext_vector_type(8))) unsigned short u16x8;
typedef __attribute__((ext_vector_type(4))) unsigned int u32x4;
typedef __attribute__((ext_vector_type(2))) float f32x2;

__device__ inline u16 f2bf(float f) {          // RTNE
    u32 u = __builtin_bit_cast(u32, f);
    return (u16)((u + 0x7FFFu + ((u >> 16) & 1u)) >> 16);
}

// ---- pass 0: x -> bf16 convert (no LDS, full occupancy) ----
__global__ __launch_bounds__(256) void convert_kernel(
    const float* __restrict__ xf, u16* __restrict__ xb, int n_elems)
{
    int i = ((int)blockIdx.x * 256 + (int)threadIdx.x) * 8;
    if (i < n_elems) {
        float4 a = *(const float4*)(xf + i);
        float4 b = *(const float4*)(xf + i + 4);
        u16x8 r;
        r[0]=f2bf(a.x); r[1]=f2bf(a.y); r[2]=f2bf(a.z); r[3]=f2bf(a.w);
        r[4]=f2bf(b.x); r[5]=f2bf(b.y); r[6]=f2bf(b.z); r[7]=f2bf(b.w);
        *(u16x8*)(xb + i) = r;
    }
}

// ---- pass 1: LDS-sorted tile partition (512 threads, reg-staged edges) ----
__global__ __launch_bounds__(PTHREADS) void partition_kernel(
    const int* __restrict__ src, const int* __restrict__ dst,
    u32* __restrict__ gcur,        // [n_bins*GSTRIDE] padded cursors (zeroed)
    u32* __restrict__ cbdata,      // [n_bins*CAPBIN] packed (nid7<<17)|src
    int n_edges, int n_bins)
{
    __shared__ u32 hist[NSCAN];        // 4 KB
    __shared__ u32 starts[NSCAN];      // 4 KB (tile-local exclusive prefix)
    __shared__ u32 lpos[NSCAN];        // 4 KB
    __shared__ u32 wcur[NB_H];         // 3.1 KB (global span base per bin)
    __shared__ u32 sortbuf[TILE];      // 16 KB
    __shared__ u16 binid[TILE];        // 8 KB
    __shared__ u32 wsum[PTHREADS / 64];

    const int tid   = threadIdx.x;
    const int tbase = (int)blockIdx.x * TILE;
    const int tend  = min(tbase + TILE, n_edges);

    for (int i = tid; i < NSCAN; i += PTHREADS) { hist[i] = 0; lpos[i] = 0; }
    __syncthreads();

    // Load each thread's EPT edges ONCE into registers; histogram as we go.
    u32 breg[EPT];                     // bin id (or ~0 for OOB)
    u32 preg[EPT];                     // packed (nid7<<17)|src
    #pragma unroll
    for (int k = 0; k < EPT; ++k) {
        int e = tbase + tid + k * PTHREADS;
        breg[k] = ~0u;
        if (e < tend) {
            int d = dst[e];
            int s = src[e];
            breg[k] = (u32)d >> BIN_SHIFT;
            preg[k] = ((u32)(d & (BIN_NODES - 1)) << 17) | (u32)s;
            atomicAdd(&hist[breg[k]], 1u);
        }
    }
    __syncthreads();

    // Tile-local exclusive scan of hist[0..NSCAN): 2 slots/thread + wave scan.
    {
        const int b0 = tid * 2;
        u32 h0 = hist[b0], h1 = hist[b0 + 1];
        u32 s  = h0 + h1;
        u32 inc = s;
        #pragma unroll
        for (int d = 1; d < 64; d <<= 1) {
            u32 o = __shfl_up(inc, d);
            if ((tid & 63) >= d) inc += o;
        }
        if ((tid & 63) == 63) wsum[tid >> 6] = inc;
        __syncthreads();
        u32 woff = 0;
        #pragma unroll
        for (int k = 0; k < PTHREADS / 64; ++k) if (k < (tid >> 6)) woff += wsum[k];
        u32 excl = woff + inc - s;
        starts[b0]     = excl;
        starts[b0 + 1] = excl + h0;
    }
    __syncthreads();

    // Reserve global spans (rotated start to spread cursor-line contention).
    const int rot = (int)(((u32)blockIdx.x * 193u) % (u32)n_bins);
    for (int i = tid; i < n_bins; i += PTHREADS) {
        int b = i + rot; if (b >= n_bins) b -= n_bins;
        u32 h = hist[b];
        if (h) wcur[b] = atomicAdd(&gcur[b * GSTRIDE], h);
    }
    __syncthreads();

    // Place from registers (no global re-read).
    #pragma unroll
    for (int k = 0; k < EPT; ++k) {
        if (breg[k] != ~0u) {
            u32 b   = breg[k];
            u32 pos = starts[b] + atomicAdd(&lpos[b], 1u);
            sortbuf[pos] = preg[k];
            binid[pos]   = (u16)b;
        }
    }
    __syncthreads();

    // Linear sweep -> run-coalesced global writes.
    const int cnt = tend - tbase;
    for (int j = tid; j < cnt; j += PTHREADS) {
        u32 b   = binid[j];
        u32 rel = wcur[b] + ((u32)j - starts[b]);
        if (rel < CAPBIN)
            cbdata[(size_t)b * CAPBIN + rel] = sortbuf[j];
    }
}

// ---- pass 2 (fused): per-bin LDS sort by (nid, src-block) + aggregate h ----
// One block per bin. Sort -> gather from LDS ids -> hb = bf16(relu(sum)),
// and write the sorted list + nodeptr for pass 3.
__global__ __launch_bounds__(256) void sort_aggregate_kernel(
    const u16* __restrict__ xin,
    u32* __restrict__ cbdata,          // in: (nid7<<17)|src   out: src (sorted)
    const u32* __restrict__ gcur,
    u32* __restrict__ nodeptr,         // [n_bins*NPTR] absolute offsets
    u16* __restrict__ out_bf,
    int n_nodes, int n_bins)
{
    __shared__ u32 hist[NSCAN];        // (nid<<3)|srcblk counters, 4 KB
    __shared__ u32 starts[NSCAN];      // 4 KB
    __shared__ u32 lpos[NSCAN];        // 4 KB
    __shared__ u32 sl[CAPBIN];         // 8 KB sorted src ids
    __shared__ u32 wsum[4];

    const int tid = threadIdx.x;
    const int bin = blockIdx.x;
    if (bin >= n_bins) return;

    for (int i = tid; i < NSCAN; i += 256) { hist[i] = 0; lpos[i] = 0; }
    __syncthreads();

    int cnt = (int)gcur[bin * GSTRIDE];
    if (cnt > CAPBIN) cnt = CAPBIN;
    u32* bd = cbdata + (size_t)bin * CAPBIN;

    for (int j = tid; j < cnt; j += 256) {             // count
        u32 p = bd[j];
        u32 key = ((p >> 17) << 3) | ((p & 0x1FFFFu) >> SRCSH);
        atomicAdd(&hist[key], 1u);
    }
    __syncthreads();

    // Exclusive scan of hist[0..1024): 4 slots/thread + wave scan.
    {
        const int b0 = tid * 4;
        u32 h0 = hist[b0], h1 = hist[b0+1], h2 = hist[b0+2], h3 = hist[b0+3];
        u32 s  = h0 + h1 + h2 + h3;
        u32 inc = s;
        #pragma unroll
        for (int d = 1; d < 64; d <<= 1) {
            u32 o = __shfl_up(inc, d);
            if ((tid & 63) >= d) inc += o;
        }
        if ((tid & 63) == 63) wsum[tid >> 6] = inc;
        __syncthreads();
        u32 woff = 0;
        #pragma unroll
        for (int k = 0; k < 4; ++k) if (k < (tid >> 6)) woff += wsum[k];
        u32 excl = woff + inc - s;
        starts[b0]   = excl;
        starts[b0+1] = excl + h0;
        starts[b0+2] = excl + h0 + h1;
        starts[b0+3] = excl + h0 + h1 + h2;
    }
    __syncthreads();

    for (int j = tid; j < cnt; j += 256) {             // place into LDS
        u32 p   = bd[j];
        u32 key = ((p >> 17) << 3) | ((p & 0x1FFFFu) >> SRCSH);
        u32 pos = starts[key] + atomicAdd(&lpos[key], 1u);
        sl[pos] = p & 0x1FFFFu;
    }
    __syncthreads();

    // Coalesced writeback of sorted ids + CSR for pass 3.
    const u32 base = (u32)bin * CAPBIN;
    for (int j = tid; j < cnt; j += 256)
        bd[j] = sl[j];
    if (tid < BIN_NODES)
        nodeptr[(size_t)bin * NPTR + tid] = base + starts[tid << 3];
    if (tid == 0)
        nodeptr[(size_t)bin * NPTR + BIN_NODES] = base + (u32)cnt;

    // Gather + accumulate: 32 groups x 4 reps cover the bin's 128 nodes.
    // Ids come from LDS (8-lane same-address broadcast -- no shfl).
    const int w    = tid >> 6;
    const int lane = tid & 63;
    const int grp  = lane >> 3;
    const int sub  = lane & 7;           // 16B chunk of the 128B bf16 row
    const char* xc = (const char*)xin;

    #pragma unroll 1
    for (int rep = 0; rep < 4; ++rep) {
        const int nid  = w * 8 + grp + rep * 32;       // 0..127
        const int node = bin * BIN_NODES + nid;
        const int s0 = (int)starts[nid << 3];
        const int s1 = (nid < BIN_NODES - 1) ? (int)starts[(nid + 1) << 3] : cnt;

        f32x2 a0={0.f,0.f}, a1={0.f,0.f}, a2={0.f,0.f}, a3={0.f,0.f};

        int jb = s0;
        for (; jb + 8 <= s1; jb += 8) {
            #pragma unroll
            for (int k = 0; k < 8; ++k) {
                u32 s = sl[jb + k];
                u32x4 v = *(const u32x4*)(xc + ((size_t)s << 7) + (sub << 4));
                a0 += (f32x2){ __builtin_bit_cast(float, v[0] << 16),
                               __builtin_bit_cast(float, v[0] & 0xFFFF0000u) };
                a1 += (f32x2){ __builtin_bit_cast(float, v[1] << 16),
                               __builtin_bit_cast(float, v[1] & 0xFFFF0000u) };
                a2 += (f32x2){ __builtin_bit_cast(float, v[2] << 16),
                               __builtin_bit_cast(float, v[2] & 0xFFFF0000u) };
                a3 += (f32x2){ __builtin_bit_cast(float, v[3] << 16),
                               __builtin_bit_cast(float, v[3] & 0xFFFF0000u) };
            }
        }
        #pragma unroll 1
        for (; jb < s1; ++jb) {
            u32 s = sl[jb];
            u32x4 v = *(const u32x4*)(xc + ((size_t)s << 7) + (sub << 4));
            a0 += (f32x2){ __builtin_bit_cast(float, v[0] << 16),
                           __builtin_bit_cast(float, v[0] & 0xFFFF0000u) };
            a1 += (f32x2){ __builtin_bit_cast(float, v[1] << 16),
                           __builtin_bit_cast(float, v[1] & 0xFFFF0000u) };
            a2 += (f32x2){ __builtin_bit_cast(float, v[2] << 16),
                           __builtin_bit_cast(float, v[2] & 0xFFFF0000u) };
            a3 += (f32x2){ __builtin_bit_cast(float, v[3] << 16),
                           __builtin_bit_cast(float, v[3] & 0xFFFF0000u) };
        }

        if (node < n_nodes) {            // 64 lanes x 16B: 8 bf16 rows, relu'd
            u16x8 o;
            o[0]=f2bf(fmaxf(a0.x,0.f)); o[1]=f2bf(fmaxf(a0.y,0.f));
            o[2]=f2bf(fmaxf(a1.x,0.f)); o[3]=f2bf(fmaxf(a1.y,0.f));
            o[4]=f2bf(fmaxf(a2.x,0.f)); o[5]=f2bf(fmaxf(a2.y,0.f));
            o[6]=f2bf(fmaxf(a3.x,0.f)); o[7]=f2bf(fmaxf(a3.y,0.f));
            *(u16x8*)(out_bf + (size_t)node * N_FEAT + sub * 8) = o;
        }
    }
}

// ---- pass 3: aggregate h -> out (fp32), CSR spans, no LDS ----
__global__ __launch_bounds__(256) void aggregate_kernel(
    const u16* __restrict__ xin,
    const u32* __restrict__ csorted,   // sorted src ids
    const u32* __restrict__ nodeptr,
    float* __restrict__ out_f,
    int n_nodes)
{
    const int tid  = threadIdx.x;

    const int w    = tid >> 6;
    const int lane = tid & 63;
    const int grp  = lane >> 3;
    const int sub  = lane & 7;           // 16B chunk of the 128B bf16 row
    const char* xc = (const char*)xin;

    const int nl   = w * 8 + grp;        // 0..31
    const int node = (int)blockIdx.x * 32 + nl;
    const int bin  = node >> BIN_SHIFT;
    const int nid  = node & (BIN_NODES - 1);

    const int s0  = (int)nodeptr[(size_t)bin * NPTR + nid];
    const int s1  = (int)nodeptr[(size_t)bin * NPTR + nid + 1];

    f32x2 a0={0.f,0.f}, a1={0.f,0.f}, a2={0.f,0.f}, a3={0.f,0.f};

    // Full batches of 8: compile-time unroll -> 8 independent row loads in
    // flight per wave (vmcnt 7..0).
    int jb = s0;
    for (; jb + 8 <= s1; jb += 8) {
        u32 myid = csorted[jb + sub];
        #pragma unroll
        for (int k = 0; k < 8; ++k) {
            u32 s = (u32)__shfl((int)myid, (lane & 56) + k, 64);
            u32x4 v = *(const u32x4*)(xc + ((size_t)s << 7) + (sub << 4));
            a0 += (f32x2){ __builtin_bit_cast(float, v[0] << 16),
                           __builtin_bit_cast(float, v[0] & 0xFFFF0000u) };
            a1 += (f32x2){ __builtin_bit_cast(float, v[1] << 16),
                           __builtin_bit_cast(float, v[1] & 0xFFFF0000u) };
            a2 += (f32x2){ __builtin_bit_cast(float, v[2] << 16),
                           __builtin_bit_cast(float, v[2] & 0xFFFF0000u) };
            a3 += (f32x2){ __builtin_bit_cast(float, v[3] << 16),
                           __builtin_bit_cast(float, v[3] & 0xFFFF0000u) };
        }
    }
    if (jb < s1) {                       // masked tail (< 8 edges)
        u32 myid = 0;
        if (jb + sub < s1) myid = csorted[jb + sub];
        const int m = s1 - jb;
        #pragma unroll 1
        for (int k = 0; k < m; ++k) {
            u32 s = (u32)__shfl((int)myid, (lane & 56) + k, 64);
            u32x4 v = *(const u32x4*)(xc + ((size_t)s << 7) + (sub << 4));
            a0 += (f32x2){ __builtin_bit_cast(float, v[0] << 16),
                           __builtin_bit_cast(float, v[0] & 0xFFFF0000u) };
            a1 += (f32x2){ __builtin_bit_cast(float, v[1] << 16),
                           __builtin_bit_cast(float, v[1] & 0xFFFF0000u) };
            a2 += (f32x2){ __builtin_bit_cast(float, v[2] << 16),
                           __builtin_bit_cast(float, v[2] & 0xFFFF0000u) };
            a3 += (f32x2){ __builtin_bit_cast(float, v[3] << 16),
                           __builtin_bit_cast(float, v[3] & 0xFFFF0000u) };
        }
    }

    if (node < n_nodes) {                // 64 lanes x 32B: 8 fp32 rows
        float* dp = out_f + (size_t)node * N_FEAT + sub * 8;
        *(float4*)dp       = (float4){a0.x, a0.y, a1.x, a1.y};
        *(float4*)(dp + 4) = (float4){a2.x, a2.y, a3.x, a3.y};
    }
}

extern "C" void kernel_launch(void* const* d_in, const int* in_sizes, int n_in,
                              void* d_out, int out_size, void* d_ws, size_t ws_size,
                              hipStream_t stream) {
    const float* x          = (const float*)d_in[0];
    const int*   edge_index = (const int*)d_in[1];

    const int n_edges = in_sizes[1] / 2;          // (2, N_EDGES) row-major
    const int* src = edge_index;                  // row 0
    const int* dst = edge_index + n_edges;        // row 1

    const int n_nodes = out_size / N_FEAT;                      // 100000
    const int n_bins  = (n_nodes + BIN_NODES - 1) >> BIN_SHIFT; // 782
    float* out = (float*)d_out;

    const size_t xb_bytes    = (size_t)out_size * sizeof(u16);             // 12.8 MB
    const size_t hb_bytes    = (size_t)out_size * sizeof(u16);             // 12.8 MB
    const size_t cb_bytes    = (size_t)n_bins * CAPBIN * sizeof(u32);      // 6.4 MB
    const size_t np_bytes    = (size_t)n_bins * NPTR * sizeof(u32);        // 0.4 MB
    const size_t gcur_bytes  = (size_t)NB_H * GSTRIDE * sizeof(u32);       // 50 KB

    char* w = (char*)d_ws;
    u16* xb      = (u16*)w;              w += xb_bytes;
    u16* hb      = (u16*)w;              w += hb_bytes;
    u32* cbdata  = (u32*)w;              w += cb_bytes;
    u32* nodeptr = (u32*)w;              w += np_bytes;
    u32* gcur    = (u32*)w;

    hipMemsetAsync(gcur, 0, gcur_bytes, stream);

    const int conv_blocks = (out_size / 8 + 255) / 256;      // 3125
    convert_kernel<<<conv_blocks, 256, 0, stream>>>(x, xb, out_size);

    const int part_blocks = (n_edges + TILE - 1) / TILE;     // 306
    partition_kernel<<<part_blocks, PTHREADS, 0, stream>>>(
        src, dst, gcur, cbdata, n_edges, n_bins);

    sort_aggregate_kernel<<<n_bins, 256, 0, stream>>>(
        xb, cbdata, gcur, nodeptr, hb, n_nodes, n_bins);

    const int agg_blocks = (n_nodes + 31) / 32;              // 3125
    aggregate_kernel<<<agg_blocks, 256, 0, stream>>>(hb, cbdata, nodeptr, out, n_nodes);
}

// Round 12
// 153.708 us; speedup vs baseline: 1.0641x; 1.0545x over previous
//
#include <hip/hip_runtime.h>
#include <hip/hip_bf16.h>

// LightGCN: two rounds of edge aggregation.
//   h[i]   = sum_{e: dst[e]==i} x[src[e]]
//   out[i] = sum_{e: dst[e]==i} relu(h)[src[e]]
//
// Round 24 (deterministic tile slabs: no atomics, no scattered writes):
//   Partition sat at ~40us across R12-R23, invariant to every in-structure
//   change. The two never-removed global hazards: contended cursor-reserve
//   RMWs and scattered span writes into bin-contiguous cbdata. Remove both:
//   each tile block writes its LDS-sorted edges CONTIGUOUSLY to its own
//   slab (ebdata[tile*TILE ...], fully coalesced) + a per-tile u16 offset
//   table ts16[tile][784]. sort_agg gathers bin b's 306 spans from the
//   slabs -- scattered CLEAN READS (no line-RMW, high MLP from 782 blocks)
//   replacing the scattered writes, and its two global sweeps over bin data
//   become LDS sweeps. gcur + memset eliminated; zero global atomics in the
//   whole pipeline.
//   - sort_agg: span-gather -> LDS (nid,srcblk) counting sort -> gather
//     rows -> hb = bf16(relu(sum)); writes sorted ids + nodeptr for agg1.
//   - agg1: R21 batch-8 unrolled gathers (8 loads in flight).
//   - ReLU folded into sort_agg's bf16 write.

#define N_FEAT    64
#define BIN_SHIFT 7
#define BIN_NODES 128
#define CAPBIN    2048             // edges per bin (mean 1600, +11 sigma)
#define NSCAN     1024             // padded hist size for scans
#define TILE      4096
#define PTHREADS  512
#define EPT       8                // edges per thread (TILE/PTHREADS)
#define NPTR      (BIN_NODES + 1)  // nodeptr entries per bin
#define TSP       784              // ts16 stride (>= n_bins+1, even)
#define SRCSH     14               // src subkey shift: 8 blocks of 16K nodes

typedef unsigned int u32;
typedef unsigned short u16;
typedef __attribute__((ext_vector_type(8))) unsigned short u16x8;
typedef __attribute__((ext_vector_type(4))) unsigned int u32x4;
typedef __attribute__((ext_vector_type(2))) float f32x2;

__device__ inline u16 f2bf(float f) {          // RTNE
    u32 u = __builtin_bit_cast(u32, f);
    return (u16)((u + 0x7FFFu + ((u >> 16) & 1u)) >> 16);
}

// ---- pass 0: x -> bf16 convert (no LDS, full occupancy) ----
__global__ __launch_bounds__(256) void convert_kernel(
    const float* __restrict__ xf, u16* __restrict__ xb, int n_elems)
{
    int i = ((int)blockIdx.x * 256 + (int)threadIdx.x) * 8;
    if (i < n_elems) {
        float4 a = *(const float4*)(xf + i);
        float4 b = *(const float4*)(xf + i + 4);
        u16x8 r;
        r[0]=f2bf(a.x); r[1]=f2bf(a.y); r[2]=f2bf(a.z); r[3]=f2bf(a.w);
        r[4]=f2bf(b.x); r[5]=f2bf(b.y); r[6]=f2bf(b.z); r[7]=f2bf(b.w);
        *(u16x8*)(xb + i) = r;
    }
}

// ---- pass 1: tile partition -> contiguous sorted slab + offset table ----
// No global atomics, no scattered writes: slab write is linear, ts16 is 784
// u16s per tile.
__global__ __launch_bounds__(PTHREADS) void partition_kernel(
    const int* __restrict__ src, const int* __restrict__ dst,
    u32* __restrict__ ebdata,      // [n_tiles*TILE] bin-sorted slabs
    u16* __restrict__ ts16,        // [n_tiles*TSP] tile-local bin offsets
    int n_edges)
{
    __shared__ u32 hist[NSCAN];        // 4 KB
    __shared__ u32 starts[NSCAN];      // 4 KB (tile-local exclusive prefix)
    __shared__ u32 lpos[NSCAN];        // 4 KB
    __shared__ u32 sortbuf[TILE];      // 16 KB
    __shared__ u32 wsum[PTHREADS / 64];

    const int tid   = threadIdx.x;
    const int tile  = (int)blockIdx.x;
    const int tbase = tile * TILE;
    const int tend  = min(tbase + TILE, n_edges);

    for (int i = tid; i < NSCAN; i += PTHREADS) { hist[i] = 0; lpos[i] = 0; }
    __syncthreads();

    // Load each thread's EPT edges ONCE into registers; histogram as we go.
    u32 breg[EPT];                     // bin id (or ~0 for OOB)
    u32 preg[EPT];                     // packed (nid7<<17)|src
    #pragma unroll
    for (int k = 0; k < EPT; ++k) {
        int e = tbase + tid + k * PTHREADS;
        breg[k] = ~0u;
        if (e < tend) {
            int d = dst[e];
            int s = src[e];
            breg[k] = (u32)d >> BIN_SHIFT;
            preg[k] = ((u32)(d & (BIN_NODES - 1)) << 17) | (u32)s;
            atomicAdd(&hist[breg[k]], 1u);
        }
    }
    __syncthreads();

    // Tile-local exclusive scan of hist[0..NSCAN): 2 slots/thread + wave scan.
    {
        const int b0 = tid * 2;
        u32 h0 = hist[b0], h1 = hist[b0 + 1];
        u32 s  = h0 + h1;
        u32 inc = s;
        #pragma unroll
        for (int d = 1; d < 64; d <<= 1) {
            u32 o = __shfl_up(inc, d);
            if ((tid & 63) >= d) inc += o;
        }
        if ((tid & 63) == 63) wsum[tid >> 6] = inc;
        __syncthreads();
        u32 woff = 0;
        #pragma unroll
        for (int k = 0; k < PTHREADS / 64; ++k) if (k < (tid >> 6)) woff += wsum[k];
        u32 excl = woff + inc - s;
        starts[b0]     = excl;
        starts[b0 + 1] = excl + h0;
    }
    __syncthreads();

    // Place from registers into the tile-local sorted buffer.
    #pragma unroll
    for (int k = 0; k < EPT; ++k) {
        if (breg[k] != ~0u) {
            u32 b   = breg[k];
            u32 pos = starts[b] + atomicAdd(&lpos[b], 1u);
            sortbuf[pos] = preg[k];
        }
    }
    __syncthreads();

    // Linear slab writeback (fully coalesced) + offset table.
    const int cnt = tend - tbase;
    for (int j = tid; j < cnt; j += PTHREADS)
        ebdata[(size_t)tbase + j] = sortbuf[j];
    for (int i = tid; i < TSP; i += PTHREADS)
        ts16[(size_t)tile * TSP + i] = (u16)starts[i];   // starts[>=n_bins]=cnt
}

// ---- pass 2 (fused): span-gather + LDS sort by (nid, srcblk) + aggregate ----
// One block per bin. Gather the bin's spans from all tile slabs (clean
// scattered reads), counting-sort in LDS, gather rows, write hb + sorted
// list + nodeptr for pass 3.
__global__ __launch_bounds__(256) void sort_aggregate_kernel(
    const u16* __restrict__ xin,
    const u32* __restrict__ ebdata,
    const u16* __restrict__ ts16,
    u32* __restrict__ cbdata,          // out: sorted src ids per bin
    u32* __restrict__ nodeptr,         // [n_bins*NPTR] absolute offsets
    u16* __restrict__ out_bf,
    int n_nodes, int n_bins, int n_tiles)
{
    __shared__ u32 hist[NSCAN];        // (nid<<3)|srcblk counters, 4 KB
    __shared__ u32 starts[NSCAN];      // 4 KB
    __shared__ u32 lpos[NSCAN];        // 4 KB
    __shared__ u32 ebuf[CAPBIN];       // 8 KB raw packed edges
    __shared__ u32 sl[CAPBIN];         // 8 KB sorted src ids
    __shared__ u32 wsum[4];
    __shared__ u32 ecnt;

    const int tid = threadIdx.x;
    const int bin = blockIdx.x;
    if (bin >= n_bins) return;

    for (int i = tid; i < NSCAN; i += 256) { hist[i] = 0; lpos[i] = 0; }
    if (tid == 0) ecnt = 0;
    __syncthreads();

    // Span gather: tile t's edges for this bin live at
    // ebdata[t*TILE + s0 .. t*TILE + s1).
    for (int t = tid; t < n_tiles; t += 256) {
        u32 s0 = (u32)ts16[(size_t)t * TSP + bin];
        u32 s1 = (u32)ts16[(size_t)t * TSP + bin + 1];
        int len = (int)(s1 - s0);
        if (len > 0) {
            u32 base = atomicAdd(&ecnt, (u32)len);
            const u32* sp = ebdata + (size_t)t * TILE + s0;
            for (int i = 0; i < len; ++i) {
                u32 pos = base + (u32)i;
                if (pos < CAPBIN) ebuf[pos] = sp[i];
            }
        }
    }
    __syncthreads();

    int cnt = (int)ecnt;
    if (cnt > CAPBIN) cnt = CAPBIN;

    for (int j = tid; j < cnt; j += 256) {             // count (LDS sweep)
        u32 p = ebuf[j];
        u32 key = ((p >> 17) << 3) | ((p & 0x1FFFFu) >> SRCSH);
        atomicAdd(&hist[key], 1u);
    }
    __syncthreads();

    // Exclusive scan of hist[0..1024): 4 slots/thread + wave scan.
    {
        const int b0 = tid * 4;
        u32 h0 = hist[b0], h1 = hist[b0+1], h2 = hist[b0+2], h3 = hist[b0+3];
        u32 s  = h0 + h1 + h2 + h3;
        u32 inc = s;
        #pragma unroll
        for (int d = 1; d < 64; d <<= 1) {
            u32 o = __shfl_up(inc, d);
            if ((tid & 63) >= d) inc += o;
        }
        if ((tid & 63) == 63) wsum[tid >> 6] = inc;
        __syncthreads();
        u32 woff = 0;
        #pragma unroll
        for (int k = 0; k < 4; ++k) if (k < (tid >> 6)) woff += wsum[k];
        u32 excl = woff + inc - s;
        starts[b0]   = excl;
        starts[b0+1] = excl + h0;
        starts[b0+2] = excl + h0 + h1;
        starts[b0+3] = excl + h0 + h1 + h2;
    }
    __syncthreads();

    for (int j = tid; j < cnt; j += 256) {             // place (LDS sweep)
        u32 p   = ebuf[j];
        u32 key = ((p >> 17) << 3) | ((p & 0x1FFFFu) >> SRCSH);
        u32 pos = starts[key] + atomicAdd(&lpos[key], 1u);
        sl[pos] = p & 0x1FFFFu;
    }
    __syncthreads();

    // Coalesced writeback of sorted ids + CSR for pass 3.
    const u32 base = (u32)bin * CAPBIN;
    for (int j = tid; j < cnt; j += 256)
        cbdata[(size_t)base + j] = sl[j];
    if (tid < BIN_NODES)
        nodeptr[(size_t)bin * NPTR + tid] = base + starts[tid << 3];
    if (tid == 0)
        nodeptr[(size_t)bin * NPTR + BIN_NODES] = base + (u32)cnt;

    // Gather + accumulate: 32 groups x 4 reps cover the bin's 128 nodes.
    const int w    = tid >> 6;
    const int lane = tid & 63;
    const int grp  = lane >> 3;
    const int sub  = lane & 7;           // 16B chunk of the 128B bf16 row
    const char* xc = (const char*)xin;

    #pragma unroll 1
    for (int rep = 0; rep < 4; ++rep) {
        const int nid  = w * 8 + grp + rep * 32;       // 0..127
        const int node = bin * BIN_NODES + nid;
        const int s0 = (int)starts[nid << 3];
        const int s1 = (nid < BIN_NODES - 1) ? (int)starts[(nid + 1) << 3] : cnt;

        f32x2 a0={0.f,0.f}, a1={0.f,0.f}, a2={0.f,0.f}, a3={0.f,0.f};

        int jb = s0;
        for (; jb + 8 <= s1; jb += 8) {
            #pragma unroll
            for (int k = 0; k < 8; ++k) {
                u32 s = sl[jb + k];
                u32x4 v = *(const u32x4*)(xc + ((size_t)s << 7) + (sub << 4));
                a0 += (f32x2){ __builtin_bit_cast(float, v[0] << 16),
                               __builtin_bit_cast(float, v[0] & 0xFFFF0000u) };
                a1 += (f32x2){ __builtin_bit_cast(float, v[1] << 16),
                               __builtin_bit_cast(float, v[1] & 0xFFFF0000u) };
                a2 += (f32x2){ __builtin_bit_cast(float, v[2] << 16),
                               __builtin_bit_cast(float, v[2] & 0xFFFF0000u) };
                a3 += (f32x2){ __builtin_bit_cast(float, v[3] << 16),
                               __builtin_bit_cast(float, v[3] & 0xFFFF0000u) };
            }
        }
        #pragma unroll 1
        for (; jb < s1; ++jb) {
            u32 s = sl[jb];
            u32x4 v = *(const u32x4*)(xc + ((size_t)s << 7) + (sub << 4));
            a0 += (f32x2){ __builtin_bit_cast(float, v[0] << 16),
                           __builtin_bit_cast(float, v[0] & 0xFFFF0000u) };
            a1 += (f32x2){ __builtin_bit_cast(float, v[1] << 16),
                           __builtin_bit_cast(float, v[1] & 0xFFFF0000u) };
            a2 += (f32x2){ __builtin_bit_cast(float, v[2] << 16),
                           __builtin_bit_cast(float, v[2] & 0xFFFF0000u) };
            a3 += (f32x2){ __builtin_bit_cast(float, v[3] << 16),
                           __builtin_bit_cast(float, v[3] & 0xFFFF0000u) };
        }

        if (node < n_nodes) {            // 64 lanes x 16B: 8 bf16 rows, relu'd
            u16x8 o;
            o[0]=f2bf(fmaxf(a0.x,0.f)); o[1]=f2bf(fmaxf(a0.y,0.f));
            o[2]=f2bf(fmaxf(a1.x,0.f)); o[3]=f2bf(fmaxf(a1.y,0.f));
            o[4]=f2bf(fmaxf(a2.x,0.f)); o[5]=f2bf(fmaxf(a2.y,0.f));
            o[6]=f2bf(fmaxf(a3.x,0.f)); o[7]=f2bf(fmaxf(a3.y,0.f));
            *(u16x8*)(out_bf + (size_t)node * N_FEAT + sub * 8) = o;
        }
    }
}

// ---- pass 3: aggregate h -> out (fp32), CSR spans, no LDS ----
__global__ __launch_bounds__(256) void aggregate_kernel(
    const u16* __restrict__ xin,
    const u32* __restrict__ csorted,   // sorted src ids
    const u32* __restrict__ nodeptr,
    float* __restrict__ out_f,
    int n_nodes)
{
    const int tid  = threadIdx.x;

    const int w    = tid >> 6;
    const int lane = tid & 63;
    const int grp  = lane >> 3;
    const int sub  = lane & 7;           // 16B chunk of the 128B bf16 row
    const char* xc = (const char*)xin;

    const int nl   = w * 8 + grp;        // 0..31
    const int node = (int)blockIdx.x * 32 + nl;
    const int bin  = node >> BIN_SHIFT;
    const int nid  = node & (BIN_NODES - 1);

    const int s0  = (int)nodeptr[(size_t)bin * NPTR + nid];
    const int s1  = (int)nodeptr[(size_t)bin * NPTR + nid + 1];

    f32x2 a0={0.f,0.f}, a1={0.f,0.f}, a2={0.f,0.f}, a3={0.f,0.f};

    // Full batches of 8: 8 independent row loads in flight per wave.
    int jb = s0;
    for (; jb + 8 <= s1; jb += 8) {
        u32 myid = csorted[jb + sub];
        #pragma unroll
        for (int k = 0; k < 8; ++k) {
            u32 s = (u32)__shfl((int)myid, (lane & 56) + k, 64);
            u32x4 v = *(const u32x4*)(xc + ((size_t)s << 7) + (sub << 4));
            a0 += (f32x2){ __builtin_bit_cast(float, v[0] << 16),
                           __builtin_bit_cast(float, v[0] & 0xFFFF0000u) };
            a1 += (f32x2){ __builtin_bit_cast(float, v[1] << 16),
                           __builtin_bit_cast(float, v[1] & 0xFFFF0000u) };
            a2 += (f32x2){ __builtin_bit_cast(float, v[2] << 16),
                           __builtin_bit_cast(float, v[2] & 0xFFFF0000u) };
            a3 += (f32x2){ __builtin_bit_cast(float, v[3] << 16),
                           __builtin_bit_cast(float, v[3] & 0xFFFF0000u) };
        }
    }
    if (jb < s1) {                       // masked tail (< 8 edges)
        u32 myid = 0;
        if (jb + sub < s1) myid = csorted[jb + sub];
        const int m = s1 - jb;
        #pragma unroll 1
        for (int k = 0; k < m; ++k) {
            u32 s = (u32)__shfl((int)myid, (lane & 56) + k, 64);
            u32x4 v = *(const u32x4*)(xc + ((size_t)s << 7) + (sub << 4));
            a0 += (f32x2){ __builtin_bit_cast(float, v[0] << 16),
                           __builtin_bit_cast(float, v[0] & 0xFFFF0000u) };
            a1 += (f32x2){ __builtin_bit_cast(float, v[1] << 16),
                           __builtin_bit_cast(float, v[1] & 0xFFFF0000u) };
            a2 += (f32x2){ __builtin_bit_cast(float, v[2] << 16),
                           __builtin_bit_cast(float, v[2] & 0xFFFF0000u) };
            a3 += (f32x2){ __builtin_bit_cast(float, v[3] << 16),
                           __builtin_bit_cast(float, v[3] & 0xFFFF0000u) };
        }
    }

    if (node < n_nodes) {                // 64 lanes x 32B: 8 fp32 rows
        float* dp = out_f + (size_t)node * N_FEAT + sub * 8;
        *(float4*)dp       = (float4){a0.x, a0.y, a1.x, a1.y};
        *(float4*)(dp + 4) = (float4){a2.x, a2.y, a3.x, a3.y};
    }
}

extern "C" void kernel_launch(void* const* d_in, const int* in_sizes, int n_in,
                              void* d_out, int out_size, void* d_ws, size_t ws_size,
                              hipStream_t stream) {
    const float* x          = (const float*)d_in[0];
    const int*   edge_index = (const int*)d_in[1];

    const int n_edges = in_sizes[1] / 2;          // (2, N_EDGES) row-major
    const int* src = edge_index;                  // row 0
    const int* dst = edge_index + n_edges;        // row 1

    const int n_nodes = out_size / N_FEAT;                      // 100000
    const int n_bins  = (n_nodes + BIN_NODES - 1) >> BIN_SHIFT; // 782
    const int n_tiles = (n_edges + TILE - 1) / TILE;            // 306
    float* out = (float*)d_out;

    const size_t xb_bytes = (size_t)out_size * sizeof(u16);              // 12.8 MB
    const size_t hb_bytes = (size_t)out_size * sizeof(u16);              // 12.8 MB
    const size_t eb_bytes = (size_t)n_tiles * TILE * sizeof(u32);        // 5.0 MB
    const size_t cb_bytes = (size_t)n_bins * CAPBIN * sizeof(u32);       // 6.4 MB
    const size_t ts_bytes = (size_t)n_tiles * TSP * sizeof(u16);         // 0.5 MB
    const size_t np_bytes = (size_t)n_bins * NPTR * sizeof(u32);         // 0.4 MB

    char* w = (char*)d_ws;
    u16* xb      = (u16*)w;              w += xb_bytes;
    u16* hb      = (u16*)w;              w += hb_bytes;
    u32* ebdata  = (u32*)w;              w += eb_bytes;
    u32* cbdata  = (u32*)w;              w += cb_bytes;
    u16* ts16    = (u16*)w;              w += ts_bytes;
    u32* nodeptr = (u32*)w;              w += np_bytes;

    const int conv_blocks = (out_size / 8 + 255) / 256;      // 3125
    convert_kernel<<<conv_blocks, 256, 0, stream>>>(x, xb, out_size);

    partition_kernel<<<n_tiles, PTHREADS, 0, stream>>>(
        src, dst, ebdata, ts16, n_edges);

    sort_aggregate_kernel<<<n_bins, 256, 0, stream>>>(
        xb, ebdata, ts16, cbdata, nodeptr, hb, n_nodes, n_bins, n_tiles);

    const int agg_blocks = (n_nodes + 31) / 32;              // 3125
    aggregate_kernel<<<agg_blocks, 256, 0, stream>>>(hb, cbdata, nodeptr, out, n_nodes);
}

// Round 13
// 145.243 us; speedup vs baseline: 1.1261x; 1.0583x over previous
//
#include <hip/hip_runtime.h>
#include <hip/hip_bf16.h>

// LightGCN: two rounds of edge aggregation.
//   h[i]   = sum_{e: dst[e]==i} x[src[e]]
//   out[i] = sum_{e: dst[e]==i} relu(h)[src[e]]
//
// Round 25 (512-thread sort_agg + MLP span-gather):
//   R24 (slab partition, zero atomics/scattered writes) won -8.4us and
//   exposed sort_agg as the top dispatch: 44.1us at 25% occupancy --
//   GRID-limited (782 blocks x 4 waves = 12 waves/CU ceiling) with a
//   serial span-gather (rolled runtime-len loop = 1 outstanding scattered
//   load/thread, the same anti-pattern R21 fixed in agg).
//   (a) 512 threads/block: 24 waves/CU ceiling, same 28KB LDS; row-gather
//       becomes 64 groups x 2 reps.
//   (b) span-gather: predicated 8-wide register batches (8 loads in
//       flight) + histogram folded into the same sweep (one fewer LDS
//       pass over 1600 elements).
//   - partition: deterministic tile slabs (R24). agg1: R21 batch-8.
//   - ReLU folded into sort_agg's bf16 write.

#define N_FEAT    64
#define BIN_SHIFT 7
#define BIN_NODES 128
#define CAPBIN    2048             // edges per bin (mean 1600, +11 sigma)
#define NSCAN     1024             // padded hist size for scans
#define TILE      4096
#define PTHREADS  512
#define EPT       8                // edges per thread (TILE/PTHREADS)
#define STHREADS  512              // sort_agg threads
#define NPTR      (BIN_NODES + 1)  // nodeptr entries per bin
#define TSP       784              // ts16 stride (>= n_bins+1, even)
#define SRCSH     14               // src subkey shift: 8 blocks of 16K nodes

typedef unsigned int u32;
typedef unsigned short u16;
typedef __attribute__((ext_vector_type(8))) unsigned short u16x8;
typedef __attribute__((ext_vector_type(4))) unsigned int u32x4;
typedef __attribute__((ext_vector_type(2))) float f32x2;

__device__ inline u16 f2bf(float f) {          // RTNE
    u32 u = __builtin_bit_cast(u32, f);
    return (u16)((u + 0x7FFFu + ((u >> 16) & 1u)) >> 16);
}

// ---- pass 0: x -> bf16 convert (no LDS, full occupancy) ----
__global__ __launch_bounds__(256) void convert_kernel(
    const float* __restrict__ xf, u16* __restrict__ xb, int n_elems)
{
    int i = ((int)blockIdx.x * 256 + (int)threadIdx.x) * 8;
    if (i < n_elems) {
        float4 a = *(const float4*)(xf + i);
        float4 b = *(const float4*)(xf + i + 4);
        u16x8 r;
        r[0]=f2bf(a.x); r[1]=f2bf(a.y); r[2]=f2bf(a.z); r[3]=f2bf(a.w);
        r[4]=f2bf(b.x); r[5]=f2bf(b.y); r[6]=f2bf(b.z); r[7]=f2bf(b.w);
        *(u16x8*)(xb + i) = r;
    }
}

// ---- pass 1: tile partition -> contiguous sorted slab + offset table ----
__global__ __launch_bounds__(PTHREADS) void partition_kernel(
    const int* __restrict__ src, const int* __restrict__ dst,
    u32* __restrict__ ebdata,      // [n_tiles*TILE] bin-sorted slabs
    u16* __restrict__ ts16,        // [n_tiles*TSP] tile-local bin offsets
    int n_edges)
{
    __shared__ u32 hist[NSCAN];        // 4 KB
    __shared__ u32 starts[NSCAN];      // 4 KB (tile-local exclusive prefix)
    __shared__ u32 lpos[NSCAN];        // 4 KB
    __shared__ u32 sortbuf[TILE];      // 16 KB
    __shared__ u32 wsum[PTHREADS / 64];

    const int tid   = threadIdx.x;
    const int tile  = (int)blockIdx.x;
    const int tbase = tile * TILE;
    const int tend  = min(tbase + TILE, n_edges);

    for (int i = tid; i < NSCAN; i += PTHREADS) { hist[i] = 0; lpos[i] = 0; }
    __syncthreads();

    // Load each thread's EPT edges ONCE into registers; histogram as we go.
    u32 breg[EPT];                     // bin id (or ~0 for OOB)
    u32 preg[EPT];                     // packed (nid7<<17)|src
    #pragma unroll
    for (int k = 0; k < EPT; ++k) {
        int e = tbase + tid + k * PTHREADS;
        breg[k] = ~0u;
        if (e < tend) {
            int d = dst[e];
            int s = src[e];
            breg[k] = (u32)d >> BIN_SHIFT;
            preg[k] = ((u32)(d & (BIN_NODES - 1)) << 17) | (u32)s;
            atomicAdd(&hist[breg[k]], 1u);
        }
    }
    __syncthreads();

    // Tile-local exclusive scan of hist[0..NSCAN): 2 slots/thread + wave scan.
    {
        const int b0 = tid * 2;
        u32 h0 = hist[b0], h1 = hist[b0 + 1];
        u32 s  = h0 + h1;
        u32 inc = s;
        #pragma unroll
        for (int d = 1; d < 64; d <<= 1) {
            u32 o = __shfl_up(inc, d);
            if ((tid & 63) >= d) inc += o;
        }
        if ((tid & 63) == 63) wsum[tid >> 6] = inc;
        __syncthreads();
        u32 woff = 0;
        #pragma unroll
        for (int k = 0; k < PTHREADS / 64; ++k) if (k < (tid >> 6)) woff += wsum[k];
        u32 excl = woff + inc - s;
        starts[b0]     = excl;
        starts[b0 + 1] = excl + h0;
    }
    __syncthreads();

    // Place from registers into the tile-local sorted buffer.
    #pragma unroll
    for (int k = 0; k < EPT; ++k) {
        if (breg[k] != ~0u) {
            u32 b   = breg[k];
            u32 pos = starts[b] + atomicAdd(&lpos[b], 1u);
            sortbuf[pos] = preg[k];
        }
    }
    __syncthreads();

    // Linear slab writeback (fully coalesced) + offset table.
    const int cnt = tend - tbase;
    for (int j = tid; j < cnt; j += PTHREADS)
        ebdata[(size_t)tbase + j] = sortbuf[j];
    for (int i = tid; i < TSP; i += PTHREADS)
        ts16[(size_t)tile * TSP + i] = (u16)starts[i];   // starts[>=n_bins]=cnt
}

// ---- pass 2 (fused): span-gather + LDS sort by (nid, srcblk) + aggregate ----
// One block per bin, 512 threads (24 waves/CU ceiling vs R24's 12).
__global__ __launch_bounds__(STHREADS) void sort_aggregate_kernel(
    const u16* __restrict__ xin,
    const u32* __restrict__ ebdata,
    const u16* __restrict__ ts16,
    u32* __restrict__ cbdata,          // out: sorted src ids per bin
    u32* __restrict__ nodeptr,         // [n_bins*NPTR] absolute offsets
    u16* __restrict__ out_bf,
    int n_nodes, int n_bins, int n_tiles)
{
    __shared__ u32 hist[NSCAN];        // (nid<<3)|srcblk counters, 4 KB
    __shared__ u32 starts[NSCAN];      // 4 KB
    __shared__ u32 lpos[NSCAN];        // 4 KB
    __shared__ u32 ebuf[CAPBIN];       // 8 KB raw packed edges
    __shared__ u32 sl[CAPBIN];         // 8 KB sorted src ids
    __shared__ u32 wsum[STHREADS / 64];
    __shared__ u32 ecnt;

    const int tid = threadIdx.x;
    const int bin = blockIdx.x;
    if (bin >= n_bins) return;

    for (int i = tid; i < NSCAN; i += STHREADS) { hist[i] = 0; lpos[i] = 0; }
    if (tid == 0) ecnt = 0;
    __syncthreads();

    // Span gather with MLP: predicated 8-wide register batches (8 loads in
    // flight per thread), histogram folded into the same sweep.
    if (tid < n_tiles) {
        const int t  = tid;
        u32 s0 = (u32)ts16[(size_t)t * TSP + bin];
        u32 s1 = (u32)ts16[(size_t)t * TSP + bin + 1];
        int len = (int)(s1 - s0);
        if (len > 0) {
            u32 base = atomicAdd(&ecnt, (u32)len);
            const u32* sp = ebdata + (size_t)t * TILE + s0;
            for (int i0 = 0; i0 < len; i0 += 8) {
                u32 v[8];
                #pragma unroll
                for (int k = 0; k < 8; ++k)
                    v[k] = (i0 + k < len) ? sp[i0 + k] : 0u;   // independent loads
                #pragma unroll
                for (int k = 0; k < 8; ++k) {
                    u32 pos = base + (u32)(i0 + k);
                    if (i0 + k < len && pos < CAPBIN) {
                        ebuf[pos] = v[k];
                        u32 key = ((v[k] >> 17) << 3) | ((v[k] & 0x1FFFFu) >> SRCSH);
                        atomicAdd(&hist[key], 1u);
                    }
                }
            }
        }
    }
    __syncthreads();

    int cnt = (int)ecnt;
    if (cnt > CAPBIN) cnt = CAPBIN;

    // Exclusive scan of hist[0..1024): 2 slots/thread + wave scan.
    {
        const int b0 = tid * 2;
        u32 h0 = hist[b0], h1 = hist[b0 + 1];
        u32 s  = h0 + h1;
        u32 inc = s;
        #pragma unroll
        for (int d = 1; d < 64; d <<= 1) {
            u32 o = __shfl_up(inc, d);
            if ((tid & 63) >= d) inc += o;
        }
        if ((tid & 63) == 63) wsum[tid >> 6] = inc;
        __syncthreads();
        u32 woff = 0;
        #pragma unroll
        for (int k = 0; k < STHREADS / 64; ++k) if (k < (tid >> 6)) woff += wsum[k];
        u32 excl = woff + inc - s;
        starts[b0]     = excl;
        starts[b0 + 1] = excl + h0;
    }
    __syncthreads();

    for (int j = tid; j < cnt; j += STHREADS) {        // place (LDS sweep)
        u32 p   = ebuf[j];
        u32 key = ((p >> 17) << 3) | ((p & 0x1FFFFu) >> SRCSH);
        u32 pos = starts[key] + atomicAdd(&lpos[key], 1u);
        sl[pos] = p & 0x1FFFFu;
    }
    __syncthreads();

    // Coalesced writeback of sorted ids + CSR for pass 3.
    const u32 base = (u32)bin * CAPBIN;
    for (int j = tid; j < cnt; j += STHREADS)
        cbdata[(size_t)base + j] = sl[j];
    if (tid < BIN_NODES)
        nodeptr[(size_t)bin * NPTR + tid] = base + starts[tid << 3];
    if (tid == 0)
        nodeptr[(size_t)bin * NPTR + BIN_NODES] = base + (u32)cnt;

    // Gather + accumulate: 64 groups x 2 reps cover the bin's 128 nodes.
    const int w    = tid >> 6;           // 0..7
    const int lane = tid & 63;
    const int grp  = lane >> 3;
    const int sub  = lane & 7;           // 16B chunk of the 128B bf16 row
    const char* xc = (const char*)xin;

    #pragma unroll 1
    for (int rep = 0; rep < 2; ++rep) {
        const int nid  = w * 8 + grp + rep * 64;       // 0..127
        const int node = bin * BIN_NODES + nid;
        const int s0 = (int)starts[nid << 3];
        const int s1 = (nid < BIN_NODES - 1) ? (int)starts[(nid + 1) << 3] : cnt;

        f32x2 a0={0.f,0.f}, a1={0.f,0.f}, a2={0.f,0.f}, a3={0.f,0.f};

        int jb = s0;
        for (; jb + 8 <= s1; jb += 8) {
            #pragma unroll
            for (int k = 0; k < 8; ++k) {
                u32 s = sl[jb + k];
                u32x4 v = *(const u32x4*)(xc + ((size_t)s << 7) + (sub << 4));
                a0 += (f32x2){ __builtin_bit_cast(float, v[0] << 16),
                               __builtin_bit_cast(float, v[0] & 0xFFFF0000u) };
                a1 += (f32x2){ __builtin_bit_cast(float, v[1] << 16),
                               __builtin_bit_cast(float, v[1] & 0xFFFF0000u) };
                a2 += (f32x2){ __builtin_bit_cast(float, v[2] << 16),
                               __builtin_bit_cast(float, v[2] & 0xFFFF0000u) };
                a3 += (f32x2){ __builtin_bit_cast(float, v[3] << 16),
                               __builtin_bit_cast(float, v[3] & 0xFFFF0000u) };
            }
        }
        #pragma unroll 1
        for (; jb < s1; ++jb) {
            u32 s = sl[jb];
            u32x4 v = *(const u32x4*)(xc + ((size_t)s << 7) + (sub << 4));
            a0 += (f32x2){ __builtin_bit_cast(float, v[0] << 16),
                           __builtin_bit_cast(float, v[0] & 0xFFFF0000u) };
            a1 += (f32x2){ __builtin_bit_cast(float, v[1] << 16),
                           __builtin_bit_cast(float, v[1] & 0xFFFF0000u) };
            a2 += (f32x2){ __builtin_bit_cast(float, v[2] << 16),
                           __builtin_bit_cast(float, v[2] & 0xFFFF0000u) };
            a3 += (f32x2){ __builtin_bit_cast(float, v[3] << 16),
                           __builtin_bit_cast(float, v[3] & 0xFFFF0000u) };
        }

        if (node < n_nodes) {            // 64 lanes x 16B: 8 bf16 rows, relu'd
            u16x8 o;
            o[0]=f2bf(fmaxf(a0.x,0.f)); o[1]=f2bf(fmaxf(a0.y,0.f));
            o[2]=f2bf(fmaxf(a1.x,0.f)); o[3]=f2bf(fmaxf(a1.y,0.f));
            o[4]=f2bf(fmaxf(a2.x,0.f)); o[5]=f2bf(fmaxf(a2.y,0.f));
            o[6]=f2bf(fmaxf(a3.x,0.f)); o[7]=f2bf(fmaxf(a3.y,0.f));
            *(u16x8*)(out_bf + (size_t)node * N_FEAT + sub * 8) = o;
        }
    }
}

// ---- pass 3: aggregate h -> out (fp32), CSR spans, no LDS ----
__global__ __launch_bounds__(256) void aggregate_kernel(
    const u16* __restrict__ xin,
    const u32* __restrict__ csorted,   // sorted src ids
    const u32* __restrict__ nodeptr,
    float* __restrict__ out_f,
    int n_nodes)
{
    const int tid  = threadIdx.x;

    const int w    = tid >> 6;
    const int lane = tid & 63;
    const int grp  = lane >> 3;
    const int sub  = lane & 7;           // 16B chunk of the 128B bf16 row
    const char* xc = (const char*)xin;

    const int nl   = w * 8 + grp;        // 0..31
    const int node = (int)blockIdx.x * 32 + nl;
    const int bin  = node >> BIN_SHIFT;
    const int nid  = node & (BIN_NODES - 1);

    const int s0  = (int)nodeptr[(size_t)bin * NPTR + nid];
    const int s1  = (int)nodeptr[(size_t)bin * NPTR + nid + 1];

    f32x2 a0={0.f,0.f}, a1={0.f,0.f}, a2={0.f,0.f}, a3={0.f,0.f};

    // Full batches of 8: 8 independent row loads in flight per wave.
    int jb = s0;
    for (; jb + 8 <= s1; jb += 8) {
        u32 myid = csorted[jb + sub];
        #pragma unroll
        for (int k = 0; k < 8; ++k) {
            u32 s = (u32)__shfl((int)myid, (lane & 56) + k, 64);
            u32x4 v = *(const u32x4*)(xc + ((size_t)s << 7) + (sub << 4));
            a0 += (f32x2){ __builtin_bit_cast(float, v[0] << 16),
                           __builtin_bit_cast(float, v[0] & 0xFFFF0000u) };
            a1 += (f32x2){ __builtin_bit_cast(float, v[1] << 16),
                           __builtin_bit_cast(float, v[1] & 0xFFFF0000u) };
            a2 += (f32x2){ __builtin_bit_cast(float, v[2] << 16),
                           __builtin_bit_cast(float, v[2] & 0xFFFF0000u) };
            a3 += (f32x2){ __builtin_bit_cast(float, v[3] << 16),
                           __builtin_bit_cast(float, v[3] & 0xFFFF0000u) };
        }
    }
    if (jb < s1) {                       // masked tail (< 8 edges)
        u32 myid = 0;
        if (jb + sub < s1) myid = csorted[jb + sub];
        const int m = s1 - jb;
        #pragma unroll 1
        for (int k = 0; k < m; ++k) {
            u32 s = (u32)__shfl((int)myid, (lane & 56) + k, 64);
            u32x4 v = *(const u32x4*)(xc + ((size_t)s << 7) + (sub << 4));
            a0 += (f32x2){ __builtin_bit_cast(float, v[0] << 16),
                           __builtin_bit_cast(float, v[0] & 0xFFFF0000u) };
            a1 += (f32x2){ __builtin_bit_cast(float, v[1] << 16),
                           __builtin_bit_cast(float, v[1] & 0xFFFF0000u) };
            a2 += (f32x2){ __builtin_bit_cast(float, v[2] << 16),
                           __builtin_bit_cast(float, v[2] & 0xFFFF0000u) };
            a3 += (f32x2){ __builtin_bit_cast(float, v[3] << 16),
                           __builtin_bit_cast(float, v[3] & 0xFFFF0000u) };
        }
    }

    if (node < n_nodes) {                // 64 lanes x 32B: 8 fp32 rows
        float* dp = out_f + (size_t)node * N_FEAT + sub * 8;
        *(float4*)dp       = (float4){a0.x, a0.y, a1.x, a1.y};
        *(float4*)(dp + 4) = (float4){a2.x, a2.y, a3.x, a3.y};
    }
}

extern "C" void kernel_launch(void* const* d_in, const int* in_sizes, int n_in,
                              void* d_out, int out_size, void* d_ws, size_t ws_size,
                              hipStream_t stream) {
    const float* x          = (const float*)d_in[0];
    const int*   edge_index = (const int*)d_in[1];

    const int n_edges = in_sizes[1] / 2;          // (2, N_EDGES) row-major
    const int* src = edge_index;                  // row 0
    const int* dst = edge_index + n_edges;        // row 1

    const int n_nodes = out_size / N_FEAT;                      // 100000
    const int n_bins  = (n_nodes + BIN_NODES - 1) >> BIN_SHIFT; // 782
    const int n_tiles = (n_edges + TILE - 1) / TILE;            // 306
    float* out = (float*)d_out;

    const size_t xb_bytes = (size_t)out_size * sizeof(u16);              // 12.8 MB
    const size_t hb_bytes = (size_t)out_size * sizeof(u16);              // 12.8 MB
    const size_t eb_bytes = (size_t)n_tiles * TILE * sizeof(u32);        // 5.0 MB
    const size_t cb_bytes = (size_t)n_bins * CAPBIN * sizeof(u32);       // 6.4 MB
    const size_t ts_bytes = (size_t)n_tiles * TSP * sizeof(u16);         // 0.5 MB
    const size_t np_bytes = (size_t)n_bins * NPTR * sizeof(u32);         // 0.4 MB

    char* w = (char*)d_ws;
    u16* xb      = (u16*)w;              w += xb_bytes;
    u16* hb      = (u16*)w;              w += hb_bytes;
    u32* ebdata  = (u32*)w;              w += eb_bytes;
    u32* cbdata  = (u32*)w;              w += cb_bytes;
    u16* ts16    = (u16*)w;              w += ts_bytes;
    u32* nodeptr = (u32*)w;              w += np_bytes;

    const int conv_blocks = (out_size / 8 + 255) / 256;      // 3125
    convert_kernel<<<conv_blocks, 256, 0, stream>>>(x, xb, out_size);

    partition_kernel<<<n_tiles, PTHREADS, 0, stream>>>(
        src, dst, ebdata, ts16, n_edges);

    sort_aggregate_kernel<<<n_bins, STHREADS, 0, stream>>>(
        xb, ebdata, ts16, cbdata, nodeptr, hb, n_nodes, n_bins, n_tiles);

    const int agg_blocks = (n_nodes + 31) / 32;              // 3125
    aggregate_kernel<<<agg_blocks, 256, 0, stream>>>(hb, cbdata, nodeptr, out, n_nodes);
}